// Round 1
// baseline (18.952 us; speedup 1.0000x reference)
//
#include <hip/hip_runtime.h>

// Problem constants (from reference)
#define VCAP 1000000
#define DIM  128
#define BATCH 4096
#define BAG  20
#define NFEAT 2

// Each (feature, batch-row) output of 128 fp32 is produced by 32 lanes,
// each lane owning 4 consecutive floats (one float4 = 16 B/lane).
// 256-thread blocks handle 8 rows; grid covers F*B = 8192 rows -> 1024 blocks.
__global__ __launch_bounds__(256) void emb_pool_kernel(
    const int* __restrict__ indices,   // [F, B, L] int32
    const float* __restrict__ table0,  // [V, D]
    const float* __restrict__ table1,  // [V, D]
    float* __restrict__ out)           // [B, F*D]
{
    const int row  = blockIdx.x * 8 + (threadIdx.x >> 5);  // (f,b) pair id
    const int lane = threadIdx.x & 31;                     // 0..31 -> 4 floats each
    if (row >= NFEAT * BATCH) return;

    const int f = row >> 12;          // row / 4096
    const int b = row & (BATCH - 1);  // row % 4096

    const float* __restrict__ tab = (f == 0) ? table0 : table1;
    const int* __restrict__ idxp = indices + (size_t)row * BAG;

    float4 acc = make_float4(0.f, 0.f, 0.f, 0.f);
    #pragma unroll
    for (int l = 0; l < BAG; ++l) {
        const int idx = idxp[l];
        const float4* rp =
            reinterpret_cast<const float4*>(tab + (size_t)idx * DIM);
        const float4 v = rp[lane];
        acc.x += v.x; acc.y += v.y; acc.z += v.z; acc.w += v.w;
    }

    float4* op = reinterpret_cast<float4*>(out + (size_t)b * (NFEAT * DIM) + f * DIM);
    op[lane] = acc;
}

extern "C" void kernel_launch(void* const* d_in, const int* in_sizes, int n_in,
                              void* d_out, int out_size, void* d_ws, size_t ws_size,
                              hipStream_t stream) {
    const int*   indices = (const int*)d_in[0];
    const float* table0  = (const float*)d_in[1];
    const float* table1  = (const float*)d_in[2];
    float*       out     = (float*)d_out;

    const int rows = NFEAT * BATCH;            // 8192
    const int blocks = rows / 8;               // 1024 blocks of 256 threads
    emb_pool_kernel<<<blocks, 256, 0, stream>>>(indices, table0, table1, out);
}